// Round 10
// baseline (197.026 us; speedup 1.0000x reference)
//
#include <hip/hip_runtime.h>
#include <stdint.h>

// Problem constants: N=16384, M=1024, D=1024, fp32 in/out
#define NN 16384
#define MM 1024
#define DD 1024

typedef __attribute__((ext_vector_type(4)))  int   int4v;
typedef __attribute__((ext_vector_type(8)))  int   int8v;   // 32 fp8 = one MFMA A/B frag
typedef __attribute__((ext_vector_type(4)))  float f4;
typedef __attribute__((ext_vector_type(16))) float f16v;    // 32x32 MFMA C/D frag

// ---------------------------------------------------------------------------
// Fragment-tiled global layout (round 8): operand byte for (row, k) lives at
//   addr(row,k) = (row>>5)*32768 + (k>>6)*2048 + ((row&31) + 32*((k>>5)&1))*32 + (k&31)
// i.e. [row-tile][k-step 64][lane][32B], matching mfma_32x32x64 A/B fragments.
// GEMM loads operands straight from global into VGPRs: no LDS, no barriers.
// Any hidden within-64 k-permutation cancels (A and B share the mapping).
// ---------------------------------------------------------------------------
__device__ __forceinline__ size_t frag_addr(int row, int k) {
    return (size_t)(row >> 5) * 32768 + (size_t)((k >> 6)) * 2048
         + (size_t)((row & 31) + 32 * ((k >> 5) & 1)) * 32 + (k & 31);
}

// pack 4 fp32 -> 4 OCP e4m3 bytes in a dword (HW RNE)
__device__ __forceinline__ uint32_t pk4fp8(float a, float b, float c, float d) {
    uint32_t lo = __builtin_amdgcn_cvt_pk_fp8_f32(a, b, 0, false);
    return __builtin_amdgcn_cvt_pk_fp8_f32(c, d, lo, true);
}

// ---- fused row squared-norms + fp32->fp8 fragment-layout convert ----
__global__ __launch_bounds__(256)
void rowsq_cvt8_all(const float* __restrict__ x, const float* __restrict__ cen,
                    float* __restrict__ xsq, float* __restrict__ csq,
                    uint8_t* __restrict__ x8, uint8_t* __restrict__ c8) {
    int row  = (blockIdx.x * 256 + threadIdx.x) >> 6;
    int lane = threadIdx.x & 63;
    const float* src; float* sq; uint8_t* fb; int r;
    if (row < NN) { r = row;      src = x   + (size_t)r * DD; sq = xsq + r; fb = x8; }
    else          { r = row - NN; src = cen + (size_t)r * DD; sq = csq + r; fb = c8; }
    const f4* p = (const f4*)src;
    float s = 0.f;
    for (int i = lane; i < DD / 4; i += 64) {
        f4 v = p[i];
        s = fmaf(v.x, v.x, s); s = fmaf(v.y, v.y, s);
        s = fmaf(v.z, v.z, s); s = fmaf(v.w, v.w, s);
        *(uint32_t*)(fb + frag_addr(r, 4 * i)) = pk4fp8(v.x, v.y, v.z, v.w);
    }
#pragma unroll
    for (int off = 32; off > 0; off >>= 1) s += __shfl_down(s, off);
    if (lane == 0) *sq = s;
}

// ---- norm fp32 [k][c] -> fp8 fragment layout (col=c, k) ----
__global__ __launch_bounds__(256)
void trcvt8(const float* __restrict__ in, uint8_t* __restrict__ out) {
    __shared__ float t[32][33];
    int tx = threadIdx.x & 31, ty = threadIdx.x >> 5;  // 32 x 8
    int k0 = blockIdx.y * 32, c0 = blockIdx.x * 32;
#pragma unroll
    for (int i = 0; i < 32; i += 8)    // t[k-k0][c-c0]
        t[ty + i][tx] = in[(size_t)(k0 + ty + i) * MM + c0 + tx];
    __syncthreads();
    int c  = threadIdx.x >> 3;         // 0..31 (local col)
    int kg = (threadIdx.x & 7) * 4;    // 0,4,...,28 (local k group)
    uint32_t u = pk4fp8(t[kg + 0][c], t[kg + 1][c], t[kg + 2][c], t[kg + 3][c]);
    *(uint32_t*)(out + frag_addr(c0 + c, k0 + kg)) = u;
}

// ---- LDS-free MX-fp8 MFMA GEMM, 64x128 block tile, 8 waves x 32x32/wave ----
// Round-10 change: OCCUPANCY. Rounds 5-9 were all neutral because the 64x64
// wave tile costs ~200 VGPR -> 2 waves/SIMD -> ~18% occupancy (r4 counter):
// no TLP to hide L2 latency, so every pipelining scheme stalled the same.
// Now: 32x32/wave (acc 16 VGPR), depth-2 rotating prefetch (48 VGPR frags),
// __launch_bounds__(512,4) caps allocation at 128 -> 4 waves/SIMD resident
// (2 blocks/CU, ~50% occupancy). A-tiles shared by 4 waves, B by 2 (L1 hits).
template<bool EXP_EPI>
__global__ __launch_bounds__(512, 4)
void mfma_gemm_fp8(const uint8_t* __restrict__ A, const uint8_t* __restrict__ B,
                   void* __restrict__ Cv, const float* __restrict__ xsq,
                   const float* __restrict__ csq, const float* __restrict__ gamma_p)
{
    constexpr int NC = 1024, NSTEP = 16;   // K = 1024 = 16 x 64
    const int tid  = threadIdx.x;
    const int lane = tid & 63;
    const int wave = tid >> 6;             // 0..7
    const int l31  = lane & 31;
    const int kh   = lane >> 5;
    const int wm   = (wave >> 2) * 32;     // 2 row groups
    const int wn   = (wave & 3) * 32;      // 4 col groups

    // XCD swizzle: 2048 blocks, xcd = bid&7 (HW round-robin). Each XCD owns
    // 32 consecutive 64-row panels (x8 slice 2 MB + B 1 MB fits its 4 MB L2).
    const int bid  = blockIdx.x;           // 0..2047
    const int xcd  = bid & 7;
    const int slot = bid >> 3;             // 0..255
    const int bcol = (slot & 7) * 128;
    const int brow = ((xcd << 5) | (slot >> 3)) * 64;

    const uint8_t* aP = A + (size_t)((brow + wm) >> 5) * 32768 + (size_t)lane * 32;
    const uint8_t* bP = B + (size_t)((bcol + wn) >> 5) * 32768 + (size_t)lane * 32;

    f16v acc;
#pragma unroll
    for (int r = 0; r < 16; ++r) acc[r] = 0.f;

    int8v a[3], b[3];                      // rotating 3-buffer, prefetch distance 2
#pragma unroll
    for (int s = 0; s < 2; ++s) {          // prologue: steps 0,1 in flight
        a[s] = *(const int8v*)(aP + (size_t)s * 2048);
        b[s] = *(const int8v*)(bP + (size_t)s * 2048);
    }
#pragma unroll
    for (int s = 0; s < NSTEP; ++s) {
        const int cb = s % 3;
        if (s + 2 < NSTEP) {               // issue step s+2; 2 steps of cover
            const int nb = (s + 2) % 3;
            const size_t o = (size_t)(s + 2) * 2048;
            a[nb] = *(const int8v*)(aP + o);
            b[nb] = *(const int8v*)(bP + o);
        }
        acc = __builtin_amdgcn_mfma_scale_f32_32x32x64_f8f6f4(
            a[cb], b[cb], acc, 0, 0, 0, 0x7F7F7F7F, 0, 0x7F7F7F7F);  // fp8, scales=1
    }

    // C/D layout (32x32, m74/m101): col = lane&31, row = (reg&3)+8*(reg>>2)+4*kh
    if constexpr (EXP_EPI) {
        const float gam = gamma_p[0];      // loaded here: not live in K-loop
        const float cs  = csq[bcol + wn + l31];
        uint8_t* C = (uint8_t*)Cv;         // dens8 in fragment layout (stage-2 A)
        const int col = bcol + wn + l31;
#pragma unroll
        for (int r = 0; r < 16; ++r) {
            int rl  = (r & 3) + 8 * (r >> 2) + 4 * kh;
            int row = brow + wm + rl;
            float sq = xsq[row] + cs - 2.0f * acc[r];
            float d = __expf(-gam * sq);   // underflows to 0 (sq ~>1500)
            C[frag_addr(row, col)] =
                (uint8_t)(__builtin_amdgcn_cvt_pk_fp8_f32(d, d, 0, false) & 0xFF);
        }
    } else {
        float* C = (float*)Cv;             // fp32 row-major output
        const int col = bcol + wn + l31;
#pragma unroll
        for (int r = 0; r < 16; ++r) {
            int rl  = (r & 3) + 8 * (r >> 2) + 4 * kh;
            int row = brow + wm + rl;
            C[(size_t)row * NC + col] = acc[r];
        }
    }
}

extern "C" void kernel_launch(void* const* d_in, const int* in_sizes, int n_in,
                              void* d_out, int out_size, void* d_ws, size_t ws_size,
                              hipStream_t stream) {
    const float* inputs  = (const float*)d_in[0];   // [N, D]
    const float* centers = (const float*)d_in[1];   // [M, D]
    const float* gamma   = (const float*)d_in[2];   // [1]
    const float* norm    = (const float*)d_in[3];   // [M, M]
    float* out = (float*)d_out;                     // [N, M]

    // ws layout: xsq 64K | csq 4K | c8 1M | n8 1M | dens8 16M  (~18.1 MiB)
    char* w = (char*)d_ws;
    float*   xsq   = (float*)w;
    float*   csq   = (float*)(w + 65536);
    uint8_t* c8    = (uint8_t*)(w + 69632);
    uint8_t* n8    = (uint8_t*)(w + 69632 + (1u << 20));
    uint8_t* dens8 = (uint8_t*)(w + 69632 + (2u << 20));
    // x8 (16 MB, fragment layout) parked in d_out: dead before stage 2 writes.
    uint8_t* x8    = (uint8_t*)d_out;

    rowsq_cvt8_all<<<(NN + MM) / 4, 256, 0, stream>>>(
        inputs, centers, xsq, csq, x8, c8);
    trcvt8<<<dim3(32, 32), 256, 0, stream>>>(norm, n8);

    // stage 1: dens = exp(-g * (xsq + csq - 2 * x @ centers^T)), fragment-fp8 out
    mfma_gemm_fp8<true><<<2048, 512, 0, stream>>>(x8, c8, dens8, xsq, csq, gamma);
    // stage 2: out = dens @ norm, fp32 out
    mfma_gemm_fp8<false><<<2048, 512, 0, stream>>>(dens8, n8, out, nullptr, nullptr, nullptr);
}

// Round 11
// 162.838 us; speedup vs baseline: 1.2100x; 1.2100x over previous
//
#include <hip/hip_runtime.h>
#include <stdint.h>

// Problem constants: N=16384, M=1024, D=1024, fp32 in/out
#define NN 16384
#define MM 1024
#define DD 1024

typedef __attribute__((ext_vector_type(4)))  int   int4v;
typedef __attribute__((ext_vector_type(8)))  int   int8v;   // 32 fp8 (MX MFMA A/B frag)
typedef __attribute__((ext_vector_type(4)))  float f4;
typedef __attribute__((ext_vector_type(16))) float f16v;    // 32x32 MFMA C/D frag

// pack 4 fp32 -> 4 OCP e4m3 bytes in a dword (HW RNE)
__device__ __forceinline__ uint32_t pk4fp8(float a, float b, float c, float d) {
    uint32_t lo = __builtin_amdgcn_cvt_pk_fp8_f32(a, b, 0, false);
    return __builtin_amdgcn_cvt_pk_fp8_f32(c, d, lo, true);
}

// ---- fused prologue (ONE dispatch, round 11): blocks [0,4352) do row
// squared-norms + fp32->fp8 convert of x and centers (plain [row][k] fp8);
// blocks [4352,5376) transpose+convert norm [k][c] -> [c][k] fp8. ----
#define ROW_BLOCKS ((NN + MM) / 4)   // 4352

__global__ __launch_bounds__(256)
void prologue_kernel(const float* __restrict__ x, const float* __restrict__ cen,
                     const float* __restrict__ norm,
                     float* __restrict__ xsq, float* __restrict__ csq,
                     uint32_t* __restrict__ x8, uint32_t* __restrict__ c8,
                     uint8_t* __restrict__ n8) {
    if (blockIdx.x < ROW_BLOCKS) {
        int row  = (blockIdx.x * 256 + threadIdx.x) >> 6;
        int lane = threadIdx.x & 63;
        const float* src; float* sq; uint32_t* ob;
        if (row < NN) { src = x + (size_t)row * DD;  sq = xsq + row;
                        ob = x8 + (size_t)row * (DD / 4); }
        else          { int r = row - NN;
                        src = cen + (size_t)r * DD;  sq = csq + r;
                        ob = c8 + (size_t)r * (DD / 4); }
        const f4* p = (const f4*)src;
        float s = 0.f;
        for (int i = lane; i < DD / 4; i += 64) {
            f4 v = p[i];
            s = fmaf(v.x, v.x, s); s = fmaf(v.y, v.y, s);
            s = fmaf(v.z, v.z, s); s = fmaf(v.w, v.w, s);
            ob[i] = pk4fp8(v.x, v.y, v.z, v.w);
        }
#pragma unroll
        for (int off = 32; off > 0; off >>= 1) s += __shfl_down(s, off);
        if (lane == 0) *sq = s;
    } else {
        // norm transpose tile: 32x32
        __shared__ float t[32][33];
        int bid2 = blockIdx.x - ROW_BLOCKS;      // 0..1023
        int bx = bid2 & 31, by = bid2 >> 5;
        int tx = threadIdx.x & 31, ty = threadIdx.x >> 5;  // 32 x 8
#pragma unroll
        for (int i = 0; i < 32; i += 8)
            t[ty + i][tx] = norm[(size_t)(by * 32 + ty + i) * MM + bx * 32 + tx];
        __syncthreads();
        int c  = threadIdx.x >> 3;        // 0..31 (local col)
        int rg = (threadIdx.x & 7) * 4;   // 0,4,...,28 (local k group)
        uint32_t u = pk4fp8(t[rg + 0][c], t[rg + 1][c], t[rg + 2][c], t[rg + 3][c]);
        *(uint32_t*)&n8[(size_t)(bx * 32 + c) * MM + by * 32 + rg] = u;
    }
}

// ---- MX-fp8 MFMA GEMM (exact round-6 structure: best measured, 164.0 us) ----
// 128x128 tile, BK=128, 4 waves (2x2), 64x64/wave, 32x32x64 MX MFMA
// (4 independent acc chains/wave), reg-prefetch -> ds_write pipeline
// (32 KB LDS, ~3 blocks/CU), XOR-swizzled 16B chunks, XCD swizzle.
// A: [row][k] fp8; Bt: [col][k] fp8. EXP_EPI: C(fp8)=exp(-g*(xsq+csq-2acc));
// else C(fp32)=acc.
constexpr int BM = 128, BN = 128, BK = 128;

template<bool EXP_EPI>
__global__ __launch_bounds__(256)
void mfma_gemm_fp8(const uint8_t* __restrict__ A, const uint8_t* __restrict__ Bt,
                   void* __restrict__ Cv, const float* __restrict__ xsq,
                   const float* __restrict__ csq, const float* __restrict__ gamma_p)
{
    constexpr int K = 1024, NC = 1024, NIT = K / BK;
    __shared__ __align__(16) uint8_t sA[BM * BK];  // 16 KB, sA[r][c16]=G[r][c16^(r&7)]
    __shared__ __align__(16) uint8_t sB[BN * BK];  // 16 KB

    const int tid  = threadIdx.x;
    const int lane = tid & 63;
    const int wave = tid >> 6;        // 0..3
    const int l31  = lane & 31;
    const int kh   = lane >> 5;
    const int wm   = (wave >> 1) * 64;
    const int wn   = (wave & 1) * 64;

    // XCD swizzle (round-3 verified: FETCH 264->33 MB)
    const int bid  = blockIdx.x;           // 0..1023
    const int xcd  = bid & 7;
    const int slot = bid >> 3;
    const int bcol = (slot & 7) * 128;
    const int brow = ((xcd << 4) | (slot >> 3)) * 128;

    const int r8 = lane >> 3;
    const int c8 = lane & 7;
    const int wc = c8 ^ r8;                // XOR-swizzled LDS chunk

    const float gam = EXP_EPI ? gamma_p[0] : 0.f;

    f16v acc[2][2];
#pragma unroll
    for (int mi = 0; mi < 2; ++mi)
#pragma unroll
        for (int ni = 0; ni < 2; ++ni)
#pragma unroll
            for (int r = 0; r < 16; ++r) acc[mi][ni][r] = 0.f;

    const uint8_t* ga = A  + (size_t)(brow + wave * 32 + r8) * K + c8 * 16;
    const uint8_t* gb = Bt + (size_t)(bcol + wave * 32 + r8) * K + c8 * 16;
    uint8_t* wa = &sA[(wave * 32 + r8) * BK + wc * 16];
    uint8_t* wb = &sB[(wave * 32 + r8) * BK + wc * 16];

    // prologue: prefetch tile 0 into registers
    int4v pf[8];
#pragma unroll
    for (int i = 0; i < 4; ++i) {
        pf[i]     = *(const int4v*)(ga + (size_t)i * 8 * K);
        pf[4 + i] = *(const int4v*)(gb + (size_t)i * 8 * K);
    }

#pragma unroll
    for (int it = 0; it < NIT; ++it) {
        __syncthreads();              // all waves done reading LDS from prev iter
#pragma unroll
        for (int i = 0; i < 4; ++i) { // commit prefetched tile (waits its loads)
            *(int4v*)(wa + i * 8 * BK) = pf[i];
            *(int4v*)(wb + i * 8 * BK) = pf[4 + i];
        }
        __syncthreads();              // tile visible
        if (it + 1 < NIT) {           // issue next tile; flies during MFMAs below
            int koff = (it + 1) * BK;
#pragma unroll
            for (int i = 0; i < 4; ++i) {
                pf[i]     = *(const int4v*)(ga + koff + (size_t)i * 8 * K);
                pf[4 + i] = *(const int4v*)(gb + koff + (size_t)i * 8 * K);
            }
        }
#pragma unroll
        for (int s = 0; s < 2; ++s) { // two 64-deep k-steps per tile
            const int cb = s * 4 + kh * 2;
            int8v a[2], b[2];
#pragma unroll
            for (int mi = 0; mi < 2; ++mi) {
                int row = wm + mi * 32 + l31;
                const uint8_t* base = &sA[row * BK];
                int4v lo = *(const int4v*)(base + ((cb ^ (row & 7)) * 16));
                int4v hi = *(const int4v*)(base + (((cb + 1) ^ (row & 7)) * 16));
                a[mi] = __builtin_shufflevector(lo, hi, 0, 1, 2, 3, 4, 5, 6, 7);
            }
#pragma unroll
            for (int ni = 0; ni < 2; ++ni) {
                int col = wn + ni * 32 + l31;
                const uint8_t* base = &sB[col * BK];
                int4v lo = *(const int4v*)(base + ((cb ^ (col & 7)) * 16));
                int4v hi = *(const int4v*)(base + (((cb + 1) ^ (col & 7)) * 16));
                b[ni] = __builtin_shufflevector(lo, hi, 0, 1, 2, 3, 4, 5, 6, 7);
            }
#pragma unroll
            for (int mi = 0; mi < 2; ++mi)
#pragma unroll
                for (int ni = 0; ni < 2; ++ni)
                    acc[mi][ni] = __builtin_amdgcn_mfma_scale_f32_32x32x64_f8f6f4(
                        a[mi], b[ni], acc[mi][ni],
                        0, 0, 0, 0x7F7F7F7F, 0, 0x7F7F7F7F);  // fp8, scales=1.0
        }
    }

    // C/D layout (32x32, m74/m101): col = lane&31, row = (reg&3)+8*(reg>>2)+4*kh
    if constexpr (EXP_EPI) {
        uint8_t* C = (uint8_t*)Cv;
        float cs[2];
        cs[0] = csq[bcol + wn + l31];
        cs[1] = csq[bcol + wn + 32 + l31];
#pragma unroll
        for (int mi = 0; mi < 2; ++mi)
#pragma unroll
            for (int r = 0; r < 16; ++r) {
                int rl  = (r & 3) + 8 * (r >> 2) + 4 * kh;
                int row = brow + wm + mi * 32 + rl;
                float xs = xsq[row];
#pragma unroll
                for (int ni = 0; ni < 2; ++ni) {
                    int col = bcol + wn + ni * 32 + l31;
                    float sq = xs + cs[ni] - 2.0f * acc[mi][ni][r];
                    float d = __expf(-gam * sq);   // underflows to 0 (sq ~>1500)
                    C[(size_t)row * NC + col] =
                        (uint8_t)(__builtin_amdgcn_cvt_pk_fp8_f32(d, d, 0, false) & 0xFF);
                }
            }
    } else {
        float* C = (float*)Cv;
#pragma unroll
        for (int mi = 0; mi < 2; ++mi)
#pragma unroll
            for (int r = 0; r < 16; ++r) {
                int rl  = (r & 3) + 8 * (r >> 2) + 4 * kh;
                int row = brow + wm + mi * 32 + rl;
#pragma unroll
                for (int ni = 0; ni < 2; ++ni)
                    C[(size_t)row * NC + bcol + wn + ni * 32 + l31] = acc[mi][ni][r];
            }
    }
}

extern "C" void kernel_launch(void* const* d_in, const int* in_sizes, int n_in,
                              void* d_out, int out_size, void* d_ws, size_t ws_size,
                              hipStream_t stream) {
    const float* inputs  = (const float*)d_in[0];   // [N, D]
    const float* centers = (const float*)d_in[1];   // [M, D]
    const float* gamma   = (const float*)d_in[2];   // [1]
    const float* norm    = (const float*)d_in[3];   // [M, M]
    float* out = (float*)d_out;                     // [N, M]

    // ws layout: xsq 64K | csq 4K | c8 1M | n8 1M | dens8 16M  (~18.1 MiB)
    char* w = (char*)d_ws;
    float*   xsq   = (float*)w;
    float*   csq   = (float*)(w + 65536);
    uint8_t* c8    = (uint8_t*)(w + 69632);
    uint8_t* n8    = (uint8_t*)(w + 69632 + (1u << 20));
    uint8_t* dens8 = (uint8_t*)(w + 69632 + (2u << 20));
    // x8 (16 MB) parked in d_out: dead before stage 2 writes d_out.
    uint32_t* x8   = (uint32_t*)d_out;

    // single fused prologue dispatch (rowsq+cvt for x & centers, norm transpose)
    prologue_kernel<<<ROW_BLOCKS + 1024, 256, 0, stream>>>(
        inputs, centers, norm, xsq, csq, x8, (uint32_t*)c8, n8);

    // stage 1: dens = exp(-g * (xsq + csq - 2 * x @ centers^T)), fp8 out
    mfma_gemm_fp8<true><<<1024, 256, 0, stream>>>(
        (const uint8_t*)x8, c8, dens8, xsq, csq, gamma);
    // stage 2: out = dens @ norm (via norm^T), fp32 out
    mfma_gemm_fp8<false><<<1024, 256, 0, stream>>>(
        dens8, n8, out, nullptr, nullptr, nullptr);
}